// Round 14
// baseline (338.388 us; speedup 1.0000x reference)
//
#include <hip/hip_runtime.h>
#include <stdint.h>

typedef uint32_t u32;
typedef unsigned long long u64;
typedef float f4 __attribute__((ext_vector_type(4)));

#define WGATES 32768
#define BATCH  128
#define LAYERS 32
#define NTYPES 16
#define NC 32                           // compute-role blocks (4 gates/thread)
#define WPL (WGATES * 4)                // packed words per layer = 131072
#define F4L (WGATES * BATCH / 4)        // float4 per layer block = 1048576

// ws layout (u32 units):
//   [0,16)              tt truth tables
//   [1024, ...)         arrival counter: layer l at 1024+l*16 (single level)
//   [4096, ...)         done lines: layer l at 4096+l*2048; line j at +j*16;
//                       j=0..31 compute-dedicated (1 poller), 32..95 unpack
//   [73728, +33*WPL)    packed states S_0..S_32 (each address written once)
#define WS_ARR_OFF    1024
#define WS_DONE_OFF   4096
#define WS_S_OFF      73728
#define WS_NEED_BYTES ((size_t)(WS_S_OFF + 33 * WPL) * 4)

// Agent-scope (sc1) accesses: ONLY for sync + state release. Data reads use
// normal cached loads (each S_l address is written once per launch; consumers
// first-touch only after the producer's sc1 store reached the coherence pt).
__device__ __forceinline__ u32 agent_load(const u32* p) {
    return __hip_atomic_load(p, __ATOMIC_RELAXED, __HIP_MEMORY_SCOPE_AGENT);
}
__device__ __forceinline__ void agent_store(u32* p, u32 v) {
    __hip_atomic_store(p, v, __ATOMIC_RELAXED, __HIP_MEMORY_SCOPE_AGENT);
}
__device__ __forceinline__ void agent_store64(u64* p, u64 v) {
    __hip_atomic_store(p, v, __ATOMIC_RELAXED, __HIP_MEMORY_SCOPE_AGENT);
}
__device__ __forceinline__ u32 agent_add(u32* p, u32 v) {
    return __hip_atomic_fetch_add(p, v, __ATOMIC_RELAXED, __HIP_MEMORY_SCOPE_AGENT);
}

__device__ __forceinline__ void lut_masks(u32 tt, u32 m[16]) {
    #pragma unroll
    for (int j = 0; j < 16; ++j)
        m[j] = (u32)(((int)(tt << (31 - j))) >> 31);
}
__device__ __forceinline__ u32 lut_mux(const u32 m[16], u32 a, u32 b, u32 c, u32 d) {
    u32 na = ~a, nb = ~b, nc = ~c, nd = ~d;
    u32 v0 = (m[1]&a)|(m[0]&na),  v1 = (m[3]&a)|(m[2]&na);
    u32 v2 = (m[5]&a)|(m[4]&na),  v3 = (m[7]&a)|(m[6]&na);
    u32 v4 = (m[9]&a)|(m[8]&na),  v5 = (m[11]&a)|(m[10]&na);
    u32 v6 = (m[13]&a)|(m[12]&na),v7 = (m[15]&a)|(m[14]&na);
    u32 u0 = (b&v1)|(nb&v0), u1 = (b&v3)|(nb&v2);
    u32 u2 = (b&v5)|(nb&v4), u3 = (b&v7)|(nb&v6);
    u32 w0 = (c&u1)|(nc&u0), w1 = (c&u3)|(nc&u2);
    return (d&w1)|(nd&w0);
}

// Compute-role wait: dedicated line, tight sc1 poll (detect ~ RTT/2).
__device__ __forceinline__ void wait_own(const u32* ws, int l, int line, int tid) {
    if (tid == 0) {
        const u32* p = ws + WS_DONE_OFF + (size_t)l * 2048 + line * 16;
        while (agent_load(p) == 0) { /* tight: self-throttled by sc1 RTT */ }
    }
    __syncthreads();
    asm volatile("" ::: "memory");
}
// Unpack-role wait: shared spread line, sleepy poll (off critical path).
__device__ __forceinline__ void wait_shared(const u32* ws, int l, int line, int tid) {
    if (tid == 0) {
        const u32* p = ws + WS_DONE_OFF + (size_t)l * 2048 + (32 + line) * 16;
        while (agent_load(p) == 0) __builtin_amdgcn_s_sleep(8);
    }
    __syncthreads();
    asm volatile("" ::: "memory");
}

// ---------------------------------------------------------------------------
// pack_main: tt tables -> ws, zero all sync state, pack h0 -> S_0.
// ---------------------------------------------------------------------------
__global__ void pack_main(const float* __restrict__ feature,
                          const float* __restrict__ activation,
                          u32* __restrict__ ws) {
    int t = blockIdx.x * 256 + threadIdx.x;
    if (blockIdx.x == 0 && threadIdx.x < NTYPES) {
        u32 tt = 0;
        #pragma unroll
        for (int m = 0; m < 16; ++m)
            tt |= (activation[threadIdx.x * 16 + m] != 0.0f ? 1u : 0u) << m;
        ws[threadIdx.x] = tt;
    }
    int z = (int)blockIdx.x - 1;
    if (z >= 0 && z < 284)             // zero [1024, 73728): arr+done
        ws[1024 + z * 256 + threadIdx.x] = 0;
    float v = feature[t];
    u64 m = __ballot(v != 0.0f);
    if ((t & 63) == 0)
        ((u64*)(ws + WS_S_OFF))[t >> 6] = m;
}

// ---------------------------------------------------------------------------
// Persistent producer-consumer kernel, minimum-leg barrier.
// Blocks [0,NC): compute chain, 4 gates/thread (16 MLP gathers), single-level
//   arrival (32 pipelined RMWs on one line) -> 96-line bcast; each compute
//   block tight-polls its DEDICATED line.
// Blocks [NC,NC+NU): stream-unpack S_0..S_32, shared sleepy lines.
// ---------------------------------------------------------------------------
__global__ __launch_bounds__(256) void coop_kernel(
        const int* __restrict__ src_idx,
        const int* __restrict__ cell_type,
        u32* __restrict__ ws,
        float* __restrict__ out,
        int NU)
{
    u32* Sb = ws + WS_S_OFF;
    int tid = threadIdx.x;
    __shared__ u32 stt[NTYPES];
    if (tid < NTYPES) stt[tid] = ws[tid];
    __syncthreads();

    if ((int)blockIdx.x < NC) {
        // -------- compute role: 4 gates/thread --------
        int t0 = blockIdx.x * 256 + tid;    // thread id in [0, 8192)
        int g0 = t0 * 4;                    // first of 4 contiguous gates
        for (int l = 1; l <= LAYERS; ++l) {
            const int4* SI = (const int4*)(src_idx + (size_t)(l - 1) * WGATES * 4);
            const int*  CT = cell_type + (size_t)(l - 1) * WGATES;
            // Index loads issued BEFORE the gate (hide under the wait).
            int4 s0 = SI[g0], s1 = SI[g0 + 1], s2 = SI[g0 + 2], s3 = SI[g0 + 3];
            u32 c0 = stt[CT[g0]],     c1 = stt[CT[g0 + 1]];
            u32 c2 = stt[CT[g0 + 2]], c3 = stt[CT[g0 + 3]];
            if (l > 1) wait_own(ws, l - 1, blockIdx.x, tid);
            const uint4* Sp = (const uint4*)(Sb + (size_t)(l - 1) * WPL);
            // 16 independent gathers — issued back-to-back (MLP).
            uint4 A0 = Sp[(u32)s0.x], B0 = Sp[(u32)s0.y],
                  C0 = Sp[(u32)s0.z], D0 = Sp[(u32)s0.w];
            uint4 A1 = Sp[(u32)s1.x], B1 = Sp[(u32)s1.y],
                  C1 = Sp[(u32)s1.z], D1 = Sp[(u32)s1.w];
            uint4 A2 = Sp[(u32)s2.x], B2 = Sp[(u32)s2.y],
                  C2 = Sp[(u32)s2.z], D2 = Sp[(u32)s2.w];
            uint4 A3 = Sp[(u32)s3.x], B3 = Sp[(u32)s3.y],
                  C3 = Sp[(u32)s3.z], D3 = Sp[(u32)s3.w];
            u64* dst = (u64*)(Sb + (size_t)l * WPL) + (size_t)t0 * 8;
            u32 m[16];
            lut_masks(c0, m);
            {
                u32 r0 = lut_mux(m, A0.x, B0.x, C0.x, D0.x);
                u32 r1 = lut_mux(m, A0.y, B0.y, C0.y, D0.y);
                u32 r2 = lut_mux(m, A0.z, B0.z, C0.z, D0.z);
                u32 r3 = lut_mux(m, A0.w, B0.w, C0.w, D0.w);
                agent_store64(dst + 0, ((u64)r1 << 32) | r0);
                agent_store64(dst + 1, ((u64)r3 << 32) | r2);
            }
            lut_masks(c1, m);
            {
                u32 r0 = lut_mux(m, A1.x, B1.x, C1.x, D1.x);
                u32 r1 = lut_mux(m, A1.y, B1.y, C1.y, D1.y);
                u32 r2 = lut_mux(m, A1.z, B1.z, C1.z, D1.z);
                u32 r3 = lut_mux(m, A1.w, B1.w, C1.w, D1.w);
                agent_store64(dst + 2, ((u64)r1 << 32) | r0);
                agent_store64(dst + 3, ((u64)r3 << 32) | r2);
            }
            lut_masks(c2, m);
            {
                u32 r0 = lut_mux(m, A2.x, B2.x, C2.x, D2.x);
                u32 r1 = lut_mux(m, A2.y, B2.y, C2.y, D2.y);
                u32 r2 = lut_mux(m, A2.z, B2.z, C2.z, D2.z);
                u32 r3 = lut_mux(m, A2.w, B2.w, C2.w, D2.w);
                agent_store64(dst + 4, ((u64)r1 << 32) | r0);
                agent_store64(dst + 5, ((u64)r3 << 32) | r2);
            }
            lut_masks(c3, m);
            {
                u32 r0 = lut_mux(m, A3.x, B3.x, C3.x, D3.x);
                u32 r1 = lut_mux(m, A3.y, B3.y, C3.y, D3.y);
                u32 r2 = lut_mux(m, A3.z, B3.z, C3.z, D3.z);
                u32 r3 = lut_mux(m, A3.w, B3.w, C3.w, D3.w);
                agent_store64(dst + 6, ((u64)r1 << 32) | r0);
                agent_store64(dst + 7, ((u64)r3 << 32) | r2);
            }
            asm volatile("s_waitcnt vmcnt(0)" ::: "memory");  // stores acked
            __syncthreads();
            if (tid == 0) {
                // Single-level arrival: 32 pipelined RMWs on one line.
                if (agent_add(ws + WS_ARR_OFF + (size_t)l * 16, 1u) == (u32)(NC - 1)) {
                    u32* donep = ws + WS_DONE_OFF + (size_t)l * 2048;
                    #pragma unroll
                    for (int j = 0; j < 96; ++j)
                        agent_store(donep + j * 16, 1u);
                }
            }
        }
    } else {
        // -------- unpack role --------
        int ub = blockIdx.x - NC;
        bool sliced = (NU & 7) == 0;        // XCD-affine slicing
        int x = ub & 7;
        u32 per = (u32)(NU >> 3);
        for (int l = 0; l <= LAYERS; ++l) {
            if (l >= 1) wait_shared(ws, l, ub & 63, tid);
            const u32* Sl = Sb + (size_t)l * WPL;
            f4* ob = (f4*)(out + (size_t)l * WGATES * BATCH);
            u32 ibeg, iend, istep;
            if (sliced) {
                ibeg = (u32)x * (F4L / 8) + (u32)(ub >> 3) * 256u + tid;
                iend = (u32)x * (F4L / 8) + F4L / 8;
                istep = per * 256u;
            } else {
                ibeg = (u32)ub * 256u + tid; iend = (u32)F4L; istep = (u32)NU * 256u;
            }
            for (u32 i = ibeg; i < iend; i += istep) {
                u32 wb = Sl[i >> 3];               // cached (L2/L3-resident)
                u32 sh = (i & 7) * 4;
                f4 f;
                f.x = ((wb >> (sh    )) & 1) ? 1.0f : 0.0f;
                f.y = ((wb >> (sh + 1)) & 1) ? 1.0f : 0.0f;
                f.z = ((wb >> (sh + 2)) & 1) ? 1.0f : 0.0f;
                f.w = ((wb >> (sh + 3)) & 1) ? 1.0f : 0.0f;
                __builtin_nontemporal_store(f, ob + i);   // out never re-read
            }
        }
    }
}

// ======================= R2 fallback path (proven) =========================
__global__ void pack_kernel_fb(const float* __restrict__ feature,
                               const float* __restrict__ activation,
                               float* __restrict__ out,
                               u32* __restrict__ tt_ws,
                               u32* __restrict__ buf0) {
    int t = blockIdx.x * 256 + threadIdx.x;
    if (blockIdx.x == 0 && threadIdx.x < NTYPES) {
        u32 tt = 0;
        #pragma unroll
        for (int m = 0; m < 16; ++m)
            tt |= (activation[threadIdx.x * 16 + m] != 0.0f ? 1u : 0u) << m;
        tt_ws[threadIdx.x] = tt;
    }
    float v = feature[t];
    out[t] = v;
    u64 m = __ballot(v != 0.0f);
    if ((t & 63) == 0)
        ((u64*)buf0)[t >> 6] = m;
}

__global__ void fused_kernel_fb(const u32* __restrict__ prev,
                                u32* __restrict__ next,
                                const int* __restrict__ src_idx,
                                const int* __restrict__ cell_type,
                                const u32* __restrict__ tt_ws,
                                const u32* __restrict__ upacked,
                                float* __restrict__ uout,
                                int do_compute)
{
    int tid = threadIdx.x;
    if (do_compute && blockIdx.x < 512) {
        int gl = tid >> 2, q = tid & 3;
        int wg = blockIdx.x * 64 + gl;
        const int4 s = ((const int4*)src_idx)[wg];
        u32 tt = tt_ws[cell_type[wg]];
        u32 m[16];
        lut_masks(tt, m);
        u32 a = prev[(size_t)s.x * 4 + q];
        u32 b = prev[(size_t)s.y * 4 + q];
        u32 c = prev[(size_t)s.z * 4 + q];
        u32 d = prev[(size_t)s.w * 4 + q];
        next[(size_t)wg * 4 + q] = lut_mux(m, a, b, c, d);
        return;
    }
    if (uout == nullptr) return;
    int ub = do_compute ? (int)blockIdx.x - 512 : (int)blockIdx.x;
    #pragma unroll
    for (int r = 0; r < 2; ++r) {
        int fi = ((ub * 2 + r) * 256 + tid) * 4;
        u32 wb = upacked[fi >> 5];
        int sh = fi & 31;
        f4 f;
        f.x = ((wb >> (sh    )) & 1) ? 1.0f : 0.0f;
        f.y = ((wb >> (sh + 1)) & 1) ? 1.0f : 0.0f;
        f.z = ((wb >> (sh + 2)) & 1) ? 1.0f : 0.0f;
        f.w = ((wb >> (sh + 3)) & 1) ? 1.0f : 0.0f;
        ((f4*)uout)[fi >> 2] = f;
    }
}

static void launch_fallback(const float* feature, const float* activation,
                            const int* src_idx, const int* cell_type,
                            float* out, void* d_ws, hipStream_t stream) {
    u32* tt_ws = (u32*)d_ws;
    u32* bufA = (u32*)((char*)d_ws + 1024);
    u32* bufB = (u32*)((char*)d_ws + 1024 + WGATES * 16);
    pack_kernel_fb<<<WGATES * BATCH / 256, 256, 0, stream>>>(
        feature, activation, out, tt_ws, bufA);
    for (int l = 1; l <= LAYERS; ++l) {
        u32* prev = ((l - 1) & 1) ? bufB : bufA;
        u32* next = ((l - 1) & 1) ? bufA : bufB;
        float* uout = (l >= 2) ? out + (size_t)(l - 1) * WGATES * BATCH : nullptr;
        fused_kernel_fb<<<512 + 2048, 256, 0, stream>>>(
            prev, next,
            src_idx + (size_t)(l - 1) * WGATES * 4,
            cell_type + (size_t)(l - 1) * WGATES,
            tt_ws, prev, uout, 1);
    }
    u32* s32 = ((LAYERS - 1) & 1) ? bufA : bufB;
    fused_kernel_fb<<<2048, 256, 0, stream>>>(
        s32, s32, src_idx, cell_type, tt_ws,
        s32, out + (size_t)LAYERS * WGATES * BATCH, 0);
}

extern "C" void kernel_launch(void* const* d_in, const int* in_sizes, int n_in,
                              void* d_out, int out_size, void* d_ws, size_t ws_size,
                              hipStream_t stream) {
    const float* feature    = (const float*)d_in[0];
    const float* activation = (const float*)d_in[1];
    const int*   src_idx    = (const int*)d_in[2];
    const int*   cell_type  = (const int*)d_in[3];
    float* out = (float*)d_out;

    bool coop_ok = (ws_size >= WS_NEED_BYTES);
    int G = 0, NU = 0;
    if (coop_ok) {
        int dev = 0;
        (void)hipGetDevice(&dev);
        int numCU = 0, bpc = 0;
        if (hipDeviceGetAttribute(&numCU, hipDeviceAttributeMultiprocessorCount, dev)
                != hipSuccess) coop_ok = false;
        if (coop_ok &&
            hipOccupancyMaxActiveBlocksPerMultiprocessor(
                &bpc, (const void*)coop_kernel, 256, 0) != hipSuccess) coop_ok = false;
        if (coop_ok) {
            G = bpc * numCU;
            if (G > 2048) G = 2048;
            NU = G - NC;
            if (NU < 256) coop_ok = false;
        }
    }

    if (coop_ok) {
        u32* ws = (u32*)d_ws;
        pack_main<<<WGATES * BATCH / 256, 256, 0, stream>>>(feature, activation, ws);
        void* args[] = {(void*)&src_idx, (void*)&cell_type, (void*)&ws,
                        (void*)&out, (void*)&NU};
        hipError_t e = hipLaunchCooperativeKernel(
            (const void*)coop_kernel, dim3(G), dim3(256), args, 0, stream);
        if (e == hipSuccess) return;
        // cooperative launch rejected -> fall through
    }
    launch_fallback(feature, activation, src_idx, cell_type, out, d_ws, stream);
}

// Round 16
// 165.283 us; speedup vs baseline: 2.0473x; 2.0473x over previous
//
#include <hip/hip_runtime.h>
#include <stdint.h>

typedef uint32_t u32;
typedef unsigned long long u64;
typedef float f4 __attribute__((ext_vector_type(4)));

#define WGATES 32768
#define BATCH  128
#define LAYERS 32
#define NTYPES 16
#define WPL (WGATES * 4)                 // packed words per layer = 131072
#define SLOT (33 * WPL)                  // u32 per state buffer
#define F4L (WGATES * BATCH / 4)

// ---- common ws offsets (u32 units) ----
#define FB_SUB    1024                   // sc1 fallback: l*1024 + j*16 (j<16)
#define FB_LVL2   34816                  // l*16
#define FB_DONE   35840                  // l*1024 + j*16 (j<64)
#define PLACE_OFF 69632                  // placement-fail flag (sc1)
#define GB_ARR    69648                  // grid-barrier arrive: phase p at +p*16
#define GB_DONE   70656                  // grid-barrier done: p*1024 + j*16
#define XS_BASE   131072                 // per-XCD sync: + x*65536
#define XS_STRIDE 65536
#define XARR(l)    ((l) * 16)            // within XS block
#define XDONE(l,j) (1024 + (l) * 1536 + (j) * 16)   // j<96
#define XRANK_OFF  53248                 // per-XCD block-rank counter
#define S_OFF_X   655360                 // xcd mode: S^x at + x*SLOT
#define S_OFF_V8  69632 + 8192           // v8 mode state base (coop_v8 only)
#define WS_NEED_XCD ((size_t)(S_OFF_X + 8 * SLOT) * 4)
#define WS_NEED_V8  ((size_t)(S_OFF_V8 + SLOT) * 4)

// ---- sc1 (device/fabric) helpers — proven sync path ----
__device__ __forceinline__ u32 agent_load(const u32* p) {
    return __hip_atomic_load(p, __ATOMIC_RELAXED, __HIP_MEMORY_SCOPE_AGENT);
}
__device__ __forceinline__ void agent_store(u32* p, u32 v) {
    __hip_atomic_store(p, v, __ATOMIC_RELAXED, __HIP_MEMORY_SCOPE_AGENT);
}
__device__ __forceinline__ void agent_store64(u64* p, u64 v) {
    __hip_atomic_store(p, v, __ATOMIC_RELAXED, __HIP_MEMORY_SCOPE_AGENT);
}
__device__ __forceinline__ u32 agent_add(u32* p, u32 v) {
    return __hip_atomic_fetch_add(p, v, __ATOMIC_RELAXED, __HIP_MEMORY_SCOPE_AGENT);
}

// ---- sc0 (XCD-local L2) helpers — valid ONLY among same-XCD blocks ----
__device__ __forceinline__ u32 l2_load(const u32* p) {
    u32 v; u64 a = (u64)p;
    asm volatile("global_load_dword %0, %1, off sc0\n\ts_waitcnt vmcnt(0)"
                 : "=v"(v) : "v"(a) : "memory");
    return v;
}
__device__ __forceinline__ void l2_store(u32* p, u32 v) {
    u64 a = (u64)p;
    asm volatile("global_store_dword %0, %1, off sc0"
                 :: "v"(a), "v"(v) : "memory");
}
__device__ __forceinline__ void l2_store64(u64* p, u64 v) {
    u64 a = (u64)p;
    asm volatile("global_store_dwordx2 %0, %1, off sc0"
                 :: "v"(a), "v"(v) : "memory");
}
__device__ __forceinline__ u32 l2_add_ret(u32* p, u32 v) {
    u32 old; u64 a = (u64)p;
    asm volatile("global_atomic_add %0, %1, %2, off sc0\n\ts_waitcnt vmcnt(0)"
                 : "=v"(old) : "v"(a), "v"(v) : "memory");
    return old;
}
__device__ __forceinline__ u32 get_xcc() {
    u32 x;
    asm("s_getreg_b32 %0, hwreg(HW_REG_XCC_ID)" : "=s"(x));
    return x & 7;
}

__device__ __forceinline__ void lut_masks(u32 tt, u32 m[16]) {
    #pragma unroll
    for (int j = 0; j < 16; ++j)
        m[j] = (u32)(((int)(tt << (31 - j))) >> 31);
}
__device__ __forceinline__ u32 lut_mux(const u32 m[16], u32 a, u32 b, u32 c, u32 d) {
    u32 na = ~a, nb = ~b, nc = ~c, nd = ~d;
    u32 v0 = (m[1]&a)|(m[0]&na),  v1 = (m[3]&a)|(m[2]&na);
    u32 v2 = (m[5]&a)|(m[4]&na),  v3 = (m[7]&a)|(m[6]&na);
    u32 v4 = (m[9]&a)|(m[8]&na),  v5 = (m[11]&a)|(m[10]&na);
    u32 v6 = (m[13]&a)|(m[12]&na),v7 = (m[15]&a)|(m[14]&na);
    u32 u0 = (b&v1)|(nb&v0), u1 = (b&v3)|(nb&v2);
    u32 u2 = (b&v5)|(nb&v4), u3 = (b&v7)|(nb&v6);
    u32 w0 = (c&u1)|(nc&u0), w1 = (c&u3)|(nc&u2);
    return (d&w1)|(nd&w0);
}

__device__ __forceinline__ void unpack_f4(u32 wb, u32 sh, f4* dst) {
    f4 f;
    f.x = ((wb >> (sh    )) & 1) ? 1.0f : 0.0f;
    f.y = ((wb >> (sh + 1)) & 1) ? 1.0f : 0.0f;
    f.z = ((wb >> (sh + 2)) & 1) ? 1.0f : 0.0f;
    f.w = ((wb >> (sh + 3)) & 1) ? 1.0f : 0.0f;
    __builtin_nontemporal_store(f, dst);
}

// sc1 sleepy/fast poll on FB done lines (fallback path)
__device__ __forceinline__ void fb_wait(const u32* ws, int l, int line,
                                        int tid, int slp) {
    if (tid == 0) {
        const u32* p = ws + FB_DONE + (size_t)l * 1024 + line * 16;
        if (slp == 1) { while (agent_load(p) == 0) __builtin_amdgcn_s_sleep(1); }
        else         { while (agent_load(p) == 0) __builtin_amdgcn_s_sleep(8); }
    }
    __syncthreads();
    asm volatile("" ::: "memory");
}

// sc1 one-shot grid barrier (proven primitives; placement-independent).
__device__ __forceinline__ void grid_barrier(u32* ws, int phase, int tid,
                                             u32 nblk) {
    if (tid == 0) {
        if (agent_add(ws + GB_ARR + phase * 16, 1u) == nblk - 1u) {
            u32* donep = ws + GB_DONE + phase * 1024;
            #pragma unroll
            for (int j = 0; j < 64; ++j)
                agent_store(donep + j * 16, 1u);
        }
        const u32* p = ws + GB_DONE + phase * 1024 + (blockIdx.x & 63) * 16;
        while (agent_load(p) == 0) __builtin_amdgcn_s_sleep(8);
    }
    __syncthreads();
    asm volatile("" ::: "memory");
}

// ---------------------------------------------------------------------------
// pack_main: tt -> ws, zero sync state, pack h0 -> S_0 (mode 1: 8 copies).
// ---------------------------------------------------------------------------
__global__ void pack_main(const float* __restrict__ feature,
                          const float* __restrict__ activation,
                          u32* __restrict__ ws, int mode) {
    int t = blockIdx.x * 256 + threadIdx.x;
    if (blockIdx.x == 0 && threadIdx.x < NTYPES) {
        u32 tt = 0;
        #pragma unroll
        for (int m = 0; m < 16; ++m)
            tt |= (activation[threadIdx.x * 16 + m] != 0.0f ? 1u : 0u) << m;
        ws[threadIdx.x] = tt;
    }
    int z = (int)blockIdx.x - 1;
    if (z >= 0 && z < 288)                       // zero [1024, 74752)
        ws[1024 + z * 256 + threadIdx.x] = 0;
    if (mode == 1) {
        int z2 = (int)blockIdx.x - 400;
        if (z2 >= 0 && z2 < 2048)                // zero XCD sync region
            ws[XS_BASE + z2 * 256 + threadIdx.x] = 0;
    }
    float v = feature[t];
    u64 m = __ballot(v != 0.0f);
    if ((t & 63) == 0) {
        u32 k = (u32)(t >> 6);
        if (mode == 1) {
            #pragma unroll
            for (int x = 0; x < 8; ++x)
                ((u64*)(ws + S_OFF_X + (size_t)x * SLOT))[k] = m;
        } else {
            ((u64*)(ws + S_OFF_V8))[k] = m;
        }
    }
}

// ---------------------------------------------------------------------------
// coop_xcd v2: per-XCD replicated chain, rank-based roles.
// Phase A: each block sc0-ranks itself in its PHYSICAL XCD's counter.
// Grid barrier (sc1). Each block verifies its XCD holds exactly 256 blocks;
// else sets fail flag. Grid barrier. Flag==0 -> XCD-local path (sc0 data
// stores, sc0 sync, local L2 only). Flag!=0 -> proven sc1 path (R13).
// ---------------------------------------------------------------------------
__global__ __launch_bounds__(256) void coop_xcd(
        const int* __restrict__ src_idx,
        const int* __restrict__ cell_type,
        u32* __restrict__ ws,
        float* __restrict__ out)
{
    int tid = threadIdx.x;
    __shared__ u32 stt[NTYPES];
    __shared__ u32 s_x, s_rank, sflag;
    if (tid < NTYPES) stt[tid] = ws[tid];
    if (tid == 0) {
        u32 x = get_xcc();
        s_x = x;
        s_rank = l2_add_ret(ws + XS_BASE + (size_t)x * XS_STRIDE + XRANK_OFF, 1u);
    }
    __syncthreads();
    grid_barrier(ws, 0, tid, 2048u);
    if (tid == 0) {
        if (l2_load(ws + XS_BASE + (size_t)s_x * XS_STRIDE + XRANK_OFF) != 256u)
            agent_store(ws + PLACE_OFF, 1u);
    }
    grid_barrier(ws, 1, tid, 2048u);
    if (tid == 0) sflag = agent_load(ws + PLACE_OFF);
    __syncthreads();

    if (sflag == 0) {
        // ================= XCD-local path =================
        int xcd = s_x;
        u32 rank = s_rank;
        u32* S  = ws + S_OFF_X + (size_t)xcd * SLOT;
        u32* XS = ws + XS_BASE + (size_t)xcd * XS_STRIDE;

        if (rank < 64) {
            // ---- compute: 2 gates/thread, all traffic XCD-local ----
            int slot = (int)rank;                // 0..63
            int t0 = slot * 256 + tid;           // 0..16383
            int g0 = t0 * 2;
            for (int l = 1; l <= LAYERS; ++l) {
                const int4* SI = (const int4*)(src_idx + (size_t)(l - 1) * WGATES * 4);
                const int*  CT = cell_type + (size_t)(l - 1) * WGATES;
                int4 s0 = SI[g0], s1 = SI[g0 + 1];
                u32 c0 = stt[CT[g0]], c1 = stt[CT[g0 + 1]];
                if (l > 1) {
                    if (tid == 0)
                        while (l2_load(XS + XDONE(l - 1, slot)) == 0) {}
                    __syncthreads();
                    asm volatile("" ::: "memory");
                }
                const uint4* Sp = (const uint4*)(S + (size_t)(l - 1) * WPL);
                u64* dst = (u64*)(S + (size_t)l * WPL) + (size_t)t0 * 4;
                u32 m[16];
                {   // gate 0
                    uint4 A = Sp[(u32)s0.x], B = Sp[(u32)s0.y],
                          C = Sp[(u32)s0.z], D = Sp[(u32)s0.w];
                    lut_masks(c0, m);
                    u32 r0 = lut_mux(m, A.x, B.x, C.x, D.x);
                    u32 r1 = lut_mux(m, A.y, B.y, C.y, D.y);
                    u32 r2 = lut_mux(m, A.z, B.z, C.z, D.z);
                    u32 r3 = lut_mux(m, A.w, B.w, C.w, D.w);
                    l2_store64(dst + 0, ((u64)r1 << 32) | r0);  // sc0: lands in
                    l2_store64(dst + 1, ((u64)r3 << 32) | r2);  // local L2
                }
                {   // gate 1
                    uint4 A = Sp[(u32)s1.x], B = Sp[(u32)s1.y],
                          C = Sp[(u32)s1.z], D = Sp[(u32)s1.w];
                    lut_masks(c1, m);
                    u32 r0 = lut_mux(m, A.x, B.x, C.x, D.x);
                    u32 r1 = lut_mux(m, A.y, B.y, C.y, D.y);
                    u32 r2 = lut_mux(m, A.z, B.z, C.z, D.z);
                    u32 r3 = lut_mux(m, A.w, B.w, C.w, D.w);
                    l2_store64(dst + 2, ((u64)r1 << 32) | r0);
                    l2_store64(dst + 3, ((u64)r3 << 32) | r2);
                }
                asm volatile("s_waitcnt vmcnt(0)" ::: "memory");  // in local L2
                __syncthreads();
                if (tid == 0) {
                    if (l2_add_ret(XS + XARR(l), 1u) == 63u) {
                        #pragma unroll
                        for (int j = 0; j < 96; ++j)
                            l2_store(XS + XDONE(l, j), 1u);
                    }
                }
            }
        } else {
            // ---- unpack: XCD's gate slice [xcd*4096,(xcd+1)*4096) ----
            int uslot = (int)rank - 64;              // 0..191
            for (int l = 0; l <= LAYERS; ++l) {
                if (l >= 1) {
                    if (tid == 0)
                        while (l2_load(XS + XDONE(l, 64 + (uslot & 31))) == 0)
                            __builtin_amdgcn_s_sleep(8);
                    __syncthreads();
                    asm volatile("" ::: "memory");
                }
                const u32* Sl = S + (size_t)l * WPL;
                f4* ob = (f4*)(out + (size_t)l * WGATES * BATCH +
                               (size_t)xcd * 4096 * 128);
                for (u32 i = (u32)uslot * 256u + tid; i < (u32)(4096 * 128 / 4);
                     i += 192u * 256u) {
                    u32 f = i * 4;                    // float idx within slice
                    u32 gis = f >> 7, bit = f & 127;
                    u32 wb = Sl[((u32)xcd * 4096 + gis) * 4 + (bit >> 5)];
                    unpack_f4(wb, bit & 31, ob + i);
                }
            }
        }
        return;
    }

    // ================= sc1 fallback path (R13 structure) =================
    u32* S = ws + S_OFF_X;                   // use slot 0 as shared state
    if ((int)blockIdx.x < 128) {
        int g = blockIdx.x * 256 + tid;
        int sub = blockIdx.x & 15;
        for (int l = 1; l <= LAYERS; ++l) {
            const int4 s = ((const int4*)(src_idx + (size_t)(l - 1) * WGATES * 4))[g];
            u32 ttv = stt[cell_type[(size_t)(l - 1) * WGATES + g]];
            if (l > 1) fb_wait(ws, l - 1, sub, tid, 1);
            const uint4* Sp = (const uint4*)(S + (size_t)(l - 1) * WPL);
            uint4 A = Sp[(u32)s.x], B = Sp[(u32)s.y],
                  C = Sp[(u32)s.z], D = Sp[(u32)s.w];
            u32 m[16];
            lut_masks(ttv, m);
            u32 r0 = lut_mux(m, A.x, B.x, C.x, D.x);
            u32 r1 = lut_mux(m, A.y, B.y, C.y, D.y);
            u32 r2 = lut_mux(m, A.z, B.z, C.z, D.z);
            u32 r3 = lut_mux(m, A.w, B.w, C.w, D.w);
            u64* dst = (u64*)(S + (size_t)l * WPL + (size_t)g * 4);
            agent_store64(dst,     ((u64)r1 << 32) | r0);
            agent_store64(dst + 1, ((u64)r3 << 32) | r2);
            asm volatile("s_waitcnt vmcnt(0)" ::: "memory");
            __syncthreads();
            if (tid == 0) {
                u32* subp = ws + FB_SUB + (size_t)l * 1024 + sub * 16;
                if (agent_add(subp, 1u) == 7u) {
                    if (agent_add(ws + FB_LVL2 + (size_t)l * 16, 1u) == 15u) {
                        u32* donep = ws + FB_DONE + (size_t)l * 1024;
                        #pragma unroll
                        for (int j = 0; j < 64; ++j)
                            agent_store(donep + j * 16, 1u);
                    }
                }
            }
        }
    } else {
        int ub = blockIdx.x - 128;           // NU = 1920, %8 == 0
        int x = ub & 7;
        for (int l = 0; l <= LAYERS; ++l) {
            if (l >= 1) fb_wait(ws, l, ub & 63, tid, 8);
            const u32* Sl = S + (size_t)l * WPL;
            f4* ob = (f4*)(out + (size_t)l * WGATES * BATCH);
            u32 ibeg = (u32)x * (F4L / 8) + (u32)(ub >> 3) * 256u + tid;
            u32 iend = (u32)x * (F4L / 8) + F4L / 8;
            for (u32 i = ibeg; i < iend; i += 240u * 256u)
                unpack_f4(Sl[i >> 3], (i & 7) * 4, ob + i);
        }
    }
}

// ---------------------------------------------------------------------------
// coop_v8: R13 proven kernel (ws too small for XCD mode). State at S_OFF_V8.
// ---------------------------------------------------------------------------
__global__ __launch_bounds__(256) void coop_v8(
        const int* __restrict__ src_idx,
        const int* __restrict__ cell_type,
        u32* __restrict__ ws,
        float* __restrict__ out,
        int NU)
{
    u32* S = ws + S_OFF_V8;
    int tid = threadIdx.x;
    __shared__ u32 stt[NTYPES];
    if (tid < NTYPES) stt[tid] = ws[tid];
    __syncthreads();

    if ((int)blockIdx.x < 128) {
        int g = blockIdx.x * 256 + tid;
        int sub = blockIdx.x & 15;
        for (int l = 1; l <= LAYERS; ++l) {
            const int4 s = ((const int4*)(src_idx + (size_t)(l - 1) * WGATES * 4))[g];
            u32 ttv = stt[cell_type[(size_t)(l - 1) * WGATES + g]];
            if (l > 1) fb_wait(ws, l - 1, sub, tid, 1);
            const uint4* Sp = (const uint4*)(S + (size_t)(l - 1) * WPL);
            uint4 A = Sp[(u32)s.x], B = Sp[(u32)s.y],
                  C = Sp[(u32)s.z], D = Sp[(u32)s.w];
            u32 m[16];
            lut_masks(ttv, m);
            u32 r0 = lut_mux(m, A.x, B.x, C.x, D.x);
            u32 r1 = lut_mux(m, A.y, B.y, C.y, D.y);
            u32 r2 = lut_mux(m, A.z, B.z, C.z, D.z);
            u32 r3 = lut_mux(m, A.w, B.w, C.w, D.w);
            u64* dst = (u64*)(S + (size_t)l * WPL + (size_t)g * 4);
            agent_store64(dst,     ((u64)r1 << 32) | r0);
            agent_store64(dst + 1, ((u64)r3 << 32) | r2);
            asm volatile("s_waitcnt vmcnt(0)" ::: "memory");
            __syncthreads();
            if (tid == 0) {
                u32* subp = ws + FB_SUB + (size_t)l * 1024 + sub * 16;
                if (agent_add(subp, 1u) == 7u) {
                    if (agent_add(ws + FB_LVL2 + (size_t)l * 16, 1u) == 15u) {
                        u32* donep = ws + FB_DONE + (size_t)l * 1024;
                        #pragma unroll
                        for (int j = 0; j < 64; ++j)
                            agent_store(donep + j * 16, 1u);
                    }
                }
            }
        }
    } else {
        int ub = blockIdx.x - 128;
        bool sliced = (NU & 7) == 0;
        int x = ub & 7;
        u32 per = (u32)(NU >> 3);
        for (int l = 0; l <= LAYERS; ++l) {
            if (l >= 1) fb_wait(ws, l, ub & 63, tid, 8);
            const u32* Sl = S + (size_t)l * WPL;
            f4* ob = (f4*)(out + (size_t)l * WGATES * BATCH);
            u32 ibeg, iend, istep;
            if (sliced) {
                ibeg = (u32)x * (F4L / 8) + (u32)(ub >> 3) * 256u + tid;
                iend = (u32)x * (F4L / 8) + F4L / 8;
                istep = per * 256u;
            } else {
                ibeg = (u32)ub * 256u + tid; iend = (u32)F4L; istep = (u32)NU * 256u;
            }
            for (u32 i = ibeg; i < iend; i += istep)
                unpack_f4(Sl[i >> 3], (i & 7) * 4, ob + i);
        }
    }
}

// ======================= R2 fallback path (proven) =========================
__global__ void pack_kernel_fb(const float* __restrict__ feature,
                               const float* __restrict__ activation,
                               float* __restrict__ out,
                               u32* __restrict__ tt_ws,
                               u32* __restrict__ buf0) {
    int t = blockIdx.x * 256 + threadIdx.x;
    if (blockIdx.x == 0 && threadIdx.x < NTYPES) {
        u32 tt = 0;
        #pragma unroll
        for (int m = 0; m < 16; ++m)
            tt |= (activation[threadIdx.x * 16 + m] != 0.0f ? 1u : 0u) << m;
        tt_ws[threadIdx.x] = tt;
    }
    float v = feature[t];
    out[t] = v;
    u64 m = __ballot(v != 0.0f);
    if ((t & 63) == 0)
        ((u64*)buf0)[t >> 6] = m;
}

__global__ void fused_kernel_fb(const u32* __restrict__ prev,
                                u32* __restrict__ next,
                                const int* __restrict__ src_idx,
                                const int* __restrict__ cell_type,
                                const u32* __restrict__ tt_ws,
                                const u32* __restrict__ upacked,
                                float* __restrict__ uout,
                                int do_compute)
{
    int tid = threadIdx.x;
    if (do_compute && blockIdx.x < 512) {
        int gl = tid >> 2, q = tid & 3;
        int wg = blockIdx.x * 64 + gl;
        const int4 s = ((const int4*)src_idx)[wg];
        u32 tt = tt_ws[cell_type[wg]];
        u32 m[16];
        lut_masks(tt, m);
        u32 a = prev[(size_t)s.x * 4 + q];
        u32 b = prev[(size_t)s.y * 4 + q];
        u32 c = prev[(size_t)s.z * 4 + q];
        u32 d = prev[(size_t)s.w * 4 + q];
        next[(size_t)wg * 4 + q] = lut_mux(m, a, b, c, d);
        return;
    }
    if (uout == nullptr) return;
    int ub = do_compute ? (int)blockIdx.x - 512 : (int)blockIdx.x;
    #pragma unroll
    for (int r = 0; r < 2; ++r) {
        int fi = ((ub * 2 + r) * 256 + tid) * 4;
        u32 wb = upacked[fi >> 5];
        int sh = fi & 31;
        f4 f;
        f.x = ((wb >> (sh    )) & 1) ? 1.0f : 0.0f;
        f.y = ((wb >> (sh + 1)) & 1) ? 1.0f : 0.0f;
        f.z = ((wb >> (sh + 2)) & 1) ? 1.0f : 0.0f;
        f.w = ((wb >> (sh + 3)) & 1) ? 1.0f : 0.0f;
        ((f4*)uout)[fi >> 2] = f;
    }
}

static void launch_fallback(const float* feature, const float* activation,
                            const int* src_idx, const int* cell_type,
                            float* out, void* d_ws, hipStream_t stream) {
    u32* tt_ws = (u32*)d_ws;
    u32* bufA = (u32*)((char*)d_ws + 1024);
    u32* bufB = (u32*)((char*)d_ws + 1024 + WGATES * 16);
    pack_kernel_fb<<<WGATES * BATCH / 256, 256, 0, stream>>>(
        feature, activation, out, tt_ws, bufA);
    for (int l = 1; l <= LAYERS; ++l) {
        u32* prev = ((l - 1) & 1) ? bufB : bufA;
        u32* next = ((l - 1) & 1) ? bufA : bufB;
        float* uout = (l >= 2) ? out + (size_t)(l - 1) * WGATES * BATCH : nullptr;
        fused_kernel_fb<<<512 + 2048, 256, 0, stream>>>(
            prev, next,
            src_idx + (size_t)(l - 1) * WGATES * 4,
            cell_type + (size_t)(l - 1) * WGATES,
            tt_ws, prev, uout, 1);
    }
    u32* s32 = ((LAYERS - 1) & 1) ? bufA : bufB;
    fused_kernel_fb<<<2048, 256, 0, stream>>>(
        s32, s32, src_idx, cell_type, tt_ws,
        s32, out + (size_t)LAYERS * WGATES * BATCH, 0);
}

extern "C" void kernel_launch(void* const* d_in, const int* in_sizes, int n_in,
                              void* d_out, int out_size, void* d_ws, size_t ws_size,
                              hipStream_t stream) {
    const float* feature    = (const float*)d_in[0];
    const float* activation = (const float*)d_in[1];
    const int*   src_idx    = (const int*)d_in[2];
    const int*   cell_type  = (const int*)d_in[3];
    float* out = (float*)d_out;
    u32* ws = (u32*)d_ws;

    int dev = 0, numCU = 0;
    (void)hipGetDevice(&dev);
    bool have_dev = hipDeviceGetAttribute(
        &numCU, hipDeviceAttributeMultiprocessorCount, dev) == hipSuccess;

    // --- try XCD-replicated path ---
    if (have_dev && ws_size >= WS_NEED_XCD) {
        int bpc = 0;
        if (hipOccupancyMaxActiveBlocksPerMultiprocessor(
                &bpc, (const void*)coop_xcd, 256, 0) == hipSuccess &&
            bpc * numCU >= 2048) {
            pack_main<<<WGATES * BATCH / 256, 256, 0, stream>>>(
                feature, activation, ws, 1);
            void* args[] = {(void*)&src_idx, (void*)&cell_type,
                            (void*)&ws, (void*)&out};
            if (hipLaunchCooperativeKernel((const void*)coop_xcd,
                    dim3(2048), dim3(256), args, 0, stream) == hipSuccess)
                return;
        }
    }
    // --- proven sc1 coop path ---
    if (have_dev && ws_size >= WS_NEED_V8) {
        int bpc = 0;
        if (hipOccupancyMaxActiveBlocksPerMultiprocessor(
                &bpc, (const void*)coop_v8, 256, 0) == hipSuccess) {
            int G = bpc * numCU;
            if (G > 2048) G = 2048;
            int NU = G - 128;
            if (NU >= 256) {
                pack_main<<<WGATES * BATCH / 256, 256, 0, stream>>>(
                    feature, activation, ws, 0);
                void* args[] = {(void*)&src_idx, (void*)&cell_type,
                                (void*)&ws, (void*)&out, (void*)&NU};
                if (hipLaunchCooperativeKernel((const void*)coop_v8,
                        dim3(G), dim3(256), args, 0, stream) == hipSuccess)
                    return;
            }
        }
    }
    launch_fallback(feature, activation, src_idx, cell_type, out, d_ws, stream);
}

// Round 17
// 165.194 us; speedup vs baseline: 2.0484x; 1.0005x over previous
//
#include <hip/hip_runtime.h>
#include <stdint.h>

typedef uint32_t u32;
typedef unsigned long long u64;
typedef float f4 __attribute__((ext_vector_type(4)));

#define WGATES 32768
#define BATCH  128
#define LAYERS 32
#define NTYPES 16
#define WPL (WGATES * 4)                 // packed words per layer = 131072
#define SLOT (33 * WPL)                  // u32 per state buffer
#define F4L (WGATES * BATCH / 4)
#define SLICE_F4 (4096 * 128 / 4)        // float4 per XCD output slice/layer

// ---- common ws offsets (u32 units) ----
#define FB_SUB    1024                   // sc1 fallback: l*1024 + j*16 (j<16)
#define FB_LVL2   34816                  // l*16
#define FB_DONE   35840                  // l*1024 + j*16 (j<64)
#define PLACE_OFF 69632                  // placement-fail flag (sc1)
#define GB_ARR    69648                  // grid-barrier arrive: phase p at +p*16
#define GB_DONE   70656                  // grid-barrier done: p*1024 + j*16
#define XS_BASE   131072                 // per-XCD sync: + x*XS_STRIDE
#define XS_STRIDE 65536
// within an XS block:
#define XSUB(l,j)  ((l) * 256 + (j) * 16)            // j<8, 8 arrivals each
#define XLVL2(l)   (8448 + (l) * 16)
#define XDONE(l,j) (8704 + (l) * 1536 + (j) * 16)    // j<96
#define XRANK_OFF  60000
#define S_OFF_X   655360                 // xcd mode: S^x at + x*SLOT
#define S_OFF_V8  (69632 + 8192)         // v8 mode state base (coop_v8 only)
#define WS_NEED_XCD ((size_t)(S_OFF_X + 8 * SLOT) * 4)
#define WS_NEED_V8  ((size_t)(S_OFF_V8 + SLOT) * 4)

// ---- sc1 (device/fabric) helpers — proven sync path ----
__device__ __forceinline__ u32 agent_load(const u32* p) {
    return __hip_atomic_load(p, __ATOMIC_RELAXED, __HIP_MEMORY_SCOPE_AGENT);
}
__device__ __forceinline__ void agent_store(u32* p, u32 v) {
    __hip_atomic_store(p, v, __ATOMIC_RELAXED, __HIP_MEMORY_SCOPE_AGENT);
}
__device__ __forceinline__ void agent_store64(u64* p, u64 v) {
    __hip_atomic_store(p, v, __ATOMIC_RELAXED, __HIP_MEMORY_SCOPE_AGENT);
}
__device__ __forceinline__ u32 agent_add(u32* p, u32 v) {
    return __hip_atomic_fetch_add(p, v, __ATOMIC_RELAXED, __HIP_MEMORY_SCOPE_AGENT);
}

// ---- sc0 (XCD-local L2) helpers — valid ONLY among same-XCD blocks ----
__device__ __forceinline__ u32 l2_load(const u32* p) {
    u32 v; u64 a = (u64)p;
    asm volatile("global_load_dword %0, %1, off sc0\n\ts_waitcnt vmcnt(0)"
                 : "=v"(v) : "v"(a) : "memory");
    return v;
}
__device__ __forceinline__ void l2_store(u32* p, u32 v) {
    u64 a = (u64)p;
    asm volatile("global_store_dword %0, %1, off sc0"
                 :: "v"(a), "v"(v) : "memory");
}
__device__ __forceinline__ void l2_store64(u64* p, u64 v) {
    u64 a = (u64)p;
    asm volatile("global_store_dwordx2 %0, %1, off sc0"
                 :: "v"(a), "v"(v) : "memory");
}
__device__ __forceinline__ u32 l2_add_ret(u32* p, u32 v) {
    u32 old; u64 a = (u64)p;
    asm volatile("global_atomic_add %0, %1, %2, off sc0\n\ts_waitcnt vmcnt(0)"
                 : "=v"(old) : "v"(a), "v"(v) : "memory");
    return old;
}
__device__ __forceinline__ u32 get_xcc() {
    u32 x;
    asm("s_getreg_b32 %0, hwreg(HW_REG_XCC_ID)" : "=s"(x));
    return x & 7;
}
__device__ __forceinline__ u64 realt() {
    u64 t; asm volatile("s_memrealtime %0" : "=s"(t)); return t;
}

__device__ __forceinline__ void lut_masks(u32 tt, u32 m[16]) {
    #pragma unroll
    for (int j = 0; j < 16; ++j)
        m[j] = (u32)(((int)(tt << (31 - j))) >> 31);
}
__device__ __forceinline__ u32 lut_mux(const u32 m[16], u32 a, u32 b, u32 c, u32 d) {
    u32 na = ~a, nb = ~b, nc = ~c, nd = ~d;
    u32 v0 = (m[1]&a)|(m[0]&na),  v1 = (m[3]&a)|(m[2]&na);
    u32 v2 = (m[5]&a)|(m[4]&na),  v3 = (m[7]&a)|(m[6]&na);
    u32 v4 = (m[9]&a)|(m[8]&na),  v5 = (m[11]&a)|(m[10]&na);
    u32 v6 = (m[13]&a)|(m[12]&na),v7 = (m[15]&a)|(m[14]&na);
    u32 u0 = (b&v1)|(nb&v0), u1 = (b&v3)|(nb&v2);
    u32 u2 = (b&v5)|(nb&v4), u3 = (b&v7)|(nb&v6);
    u32 w0 = (c&u1)|(nc&u0), w1 = (c&u3)|(nc&u2);
    return (d&w1)|(nd&w0);
}

__device__ __forceinline__ void unpack_f4(u32 wb, u32 sh, f4* dst) {
    f4 f;
    f.x = ((wb >> (sh    )) & 1) ? 1.0f : 0.0f;
    f.y = ((wb >> (sh + 1)) & 1) ? 1.0f : 0.0f;
    f.z = ((wb >> (sh + 2)) & 1) ? 1.0f : 0.0f;
    f.w = ((wb >> (sh + 3)) & 1) ? 1.0f : 0.0f;
    __builtin_nontemporal_store(f, dst);
}

// sc1 sleepy/fast poll on FB done lines (fallback path)
__device__ __forceinline__ void fb_wait(const u32* ws, int l, int line,
                                        int tid, int slp) {
    if (tid == 0) {
        const u32* p = ws + FB_DONE + (size_t)l * 1024 + line * 16;
        if (slp == 1) { while (agent_load(p) == 0) __builtin_amdgcn_s_sleep(1); }
        else         { while (agent_load(p) == 0) __builtin_amdgcn_s_sleep(8); }
    }
    __syncthreads();
    asm volatile("" ::: "memory");
}

// sc1 one-shot grid barrier (proven primitives; placement-independent).
__device__ __forceinline__ void grid_barrier(u32* ws, int phase, int tid,
                                             u32 nblk) {
    if (tid == 0) {
        if (agent_add(ws + GB_ARR + phase * 16, 1u) == nblk - 1u) {
            u32* donep = ws + GB_DONE + phase * 1024;
            #pragma unroll
            for (int j = 0; j < 64; ++j)
                agent_store(donep + j * 16, 1u);
        }
        const u32* p = ws + GB_DONE + phase * 1024 + (blockIdx.x & 63) * 16;
        while (agent_load(p) == 0) __builtin_amdgcn_s_sleep(8);
    }
    __syncthreads();
    asm volatile("" ::: "memory");
}

// ---------------------------------------------------------------------------
// pack_main: tt -> ws, zero sync state, pack h0 -> S_0 (mode 1: 8 copies).
// ---------------------------------------------------------------------------
__global__ void pack_main(const float* __restrict__ feature,
                          const float* __restrict__ activation,
                          u32* __restrict__ ws, int mode) {
    int t = blockIdx.x * 256 + threadIdx.x;
    if (blockIdx.x == 0 && threadIdx.x < NTYPES) {
        u32 tt = 0;
        #pragma unroll
        for (int m = 0; m < 16; ++m)
            tt |= (activation[threadIdx.x * 16 + m] != 0.0f ? 1u : 0u) << m;
        ws[threadIdx.x] = tt;
    }
    int z = (int)blockIdx.x - 1;
    if (z >= 0 && z < 288)                       // zero [1024, 74752)
        ws[1024 + z * 256 + threadIdx.x] = 0;
    if (mode == 1) {
        int z2 = (int)blockIdx.x - 400;
        if (z2 >= 0 && z2 < 2048)                // zero XCD sync region
            ws[XS_BASE + z2 * 256 + threadIdx.x] = 0;
    }
    float v = feature[t];
    u64 m = __ballot(v != 0.0f);
    if ((t & 63) == 0) {
        u32 k = (u32)(t >> 6);
        if (mode == 1) {
            #pragma unroll
            for (int x = 0; x < 8; ++x)
                ((u64*)(ws + S_OFF_X + (size_t)x * SLOT))[k] = m;
        } else {
            ((u64*)(ws + S_OFF_V8))[k] = m;
        }
    }
}

// ---------------------------------------------------------------------------
// coop_xcd v3: rank-based roles, relaxed check (n_x>=80), two-level local
// arrival, +80us BEACON on the fallback path to discriminate which ran.
// ---------------------------------------------------------------------------
__global__ __launch_bounds__(256) void coop_xcd(
        const int* __restrict__ src_idx,
        const int* __restrict__ cell_type,
        u32* __restrict__ ws,
        float* __restrict__ out)
{
    int tid = threadIdx.x;
    __shared__ u32 stt[NTYPES];
    __shared__ u32 s_x, s_rank, s_nx, sflag;
    if (tid < NTYPES) stt[tid] = ws[tid];
    if (tid == 0) {
        u32 x = get_xcc();
        s_x = x;
        s_rank = l2_add_ret(ws + XS_BASE + (size_t)x * XS_STRIDE + XRANK_OFF, 1u);
    }
    __syncthreads();
    grid_barrier(ws, 0, tid, 2048u);
    if (tid == 0) {
        s_nx = l2_load(ws + XS_BASE + (size_t)s_x * XS_STRIDE + XRANK_OFF);
        if (s_nx < 80u) agent_store(ws + PLACE_OFF, 1u);
    }
    grid_barrier(ws, 1, tid, 2048u);
    if (tid == 0) sflag = agent_load(ws + PLACE_OFF);
    __syncthreads();

    if (sflag == 0) {
        // ================= XCD-local path =================
        int xcd = s_x;
        u32 rank = s_rank;
        u32* S  = ws + S_OFF_X + (size_t)xcd * SLOT;
        u32* XS = ws + XS_BASE + (size_t)xcd * XS_STRIDE;

        if (rank < 64) {
            // ---- compute: 2 gates/thread, all traffic XCD-local ----
            int slot = (int)rank;                // 0..63
            int t0 = slot * 256 + tid;           // 0..16383
            int g0 = t0 * 2;
            int sub = slot & 7;                  // 8 sub-lines x 8 arrivals
            for (int l = 1; l <= LAYERS; ++l) {
                const int4* SI = (const int4*)(src_idx + (size_t)(l - 1) * WGATES * 4);
                const int*  CT = cell_type + (size_t)(l - 1) * WGATES;
                int4 s0 = SI[g0], s1 = SI[g0 + 1];
                u32 c0 = stt[CT[g0]], c1 = stt[CT[g0 + 1]];
                if (l > 1) {
                    if (tid == 0)
                        while (l2_load(XS + XDONE(l - 1, slot)) == 0) {}
                    __syncthreads();
                    asm volatile("" ::: "memory");
                }
                const uint4* Sp = (const uint4*)(S + (size_t)(l - 1) * WPL);
                u64* dst = (u64*)(S + (size_t)l * WPL) + (size_t)t0 * 4;
                u32 m[16];
                {   // gate 0
                    uint4 A = Sp[(u32)s0.x], B = Sp[(u32)s0.y],
                          C = Sp[(u32)s0.z], D = Sp[(u32)s0.w];
                    lut_masks(c0, m);
                    u32 r0 = lut_mux(m, A.x, B.x, C.x, D.x);
                    u32 r1 = lut_mux(m, A.y, B.y, C.y, D.y);
                    u32 r2 = lut_mux(m, A.z, B.z, C.z, D.z);
                    u32 r3 = lut_mux(m, A.w, B.w, C.w, D.w);
                    l2_store64(dst + 0, ((u64)r1 << 32) | r0);  // sc0 -> local L2
                    l2_store64(dst + 1, ((u64)r3 << 32) | r2);
                }
                {   // gate 1
                    uint4 A = Sp[(u32)s1.x], B = Sp[(u32)s1.y],
                          C = Sp[(u32)s1.z], D = Sp[(u32)s1.w];
                    lut_masks(c1, m);
                    u32 r0 = lut_mux(m, A.x, B.x, C.x, D.x);
                    u32 r1 = lut_mux(m, A.y, B.y, C.y, D.y);
                    u32 r2 = lut_mux(m, A.z, B.z, C.z, D.z);
                    u32 r3 = lut_mux(m, A.w, B.w, C.w, D.w);
                    l2_store64(dst + 2, ((u64)r1 << 32) | r0);
                    l2_store64(dst + 3, ((u64)r3 << 32) | r2);
                }
                asm volatile("s_waitcnt vmcnt(0)" ::: "memory");  // in local L2
                __syncthreads();
                if (tid == 0) {
                    // two-level local arrival: 8x8 then lvl2 of 8
                    if (l2_add_ret(XS + XSUB(l, sub), 1u) == 7u) {
                        if (l2_add_ret(XS + XLVL2(l), 1u) == 7u) {
                            #pragma unroll
                            for (int j = 0; j < 96; ++j)
                                l2_store(XS + XDONE(l, j), 1u);
                        }
                    }
                }
            }
        } else {
            // ---- unpack: XCD's gate slice, dynamic stride q = n_x-64 ----
            int uslot = (int)rank - 64;
            u32 q = s_nx - 64u;
            for (int l = 0; l <= LAYERS; ++l) {
                if (l >= 1) {
                    if (tid == 0)
                        while (l2_load(XS + XDONE(l, 64 + (uslot & 31))) == 0)
                            __builtin_amdgcn_s_sleep(8);
                    __syncthreads();
                    asm volatile("" ::: "memory");
                }
                const u32* Sl = S + (size_t)l * WPL;
                f4* ob = (f4*)(out + (size_t)l * WGATES * BATCH +
                               (size_t)xcd * 4096 * 128);
                for (u32 i = (u32)uslot * 256u + tid; i < (u32)SLICE_F4;
                     i += q * 256u) {
                    u32 f = i * 4;                    // float idx within slice
                    u32 gis = f >> 7, bit = f & 127;
                    u32 wb = Sl[((u32)xcd * 4096 + gis) * 4 + (bit >> 5)];
                    unpack_f4(wb, bit & 31, ob + i);
                }
            }
        }
        return;
    }

    // ================= sc1 fallback path (R13 structure) + BEACON ========
    // BEACON: +80us so the branch taken is visible in dur_us.
    if (blockIdx.x == 0 && tid == 0) {
        u64 t0 = realt();                 // 100 MHz constant clock
        while (realt() - t0 < 8000ull) __builtin_amdgcn_s_sleep(8);
    }
    u32* S = ws + S_OFF_X;                   // use slot 0 as shared state
    if ((int)blockIdx.x < 128) {
        int g = blockIdx.x * 256 + tid;
        int sub = blockIdx.x & 15;
        for (int l = 1; l <= LAYERS; ++l) {
            const int4 s = ((const int4*)(src_idx + (size_t)(l - 1) * WGATES * 4))[g];
            u32 ttv = stt[cell_type[(size_t)(l - 1) * WGATES + g]];
            if (l > 1) fb_wait(ws, l - 1, sub, tid, 1);
            const uint4* Sp = (const uint4*)(S + (size_t)(l - 1) * WPL);
            uint4 A = Sp[(u32)s.x], B = Sp[(u32)s.y],
                  C = Sp[(u32)s.z], D = Sp[(u32)s.w];
            u32 m[16];
            lut_masks(ttv, m);
            u32 r0 = lut_mux(m, A.x, B.x, C.x, D.x);
            u32 r1 = lut_mux(m, A.y, B.y, C.y, D.y);
            u32 r2 = lut_mux(m, A.z, B.z, C.z, D.z);
            u32 r3 = lut_mux(m, A.w, B.w, C.w, D.w);
            u64* dst = (u64*)(S + (size_t)l * WPL + (size_t)g * 4);
            agent_store64(dst,     ((u64)r1 << 32) | r0);
            agent_store64(dst + 1, ((u64)r3 << 32) | r2);
            asm volatile("s_waitcnt vmcnt(0)" ::: "memory");
            __syncthreads();
            if (tid == 0) {
                u32* subp = ws + FB_SUB + (size_t)l * 1024 + sub * 16;
                if (agent_add(subp, 1u) == 7u) {
                    if (agent_add(ws + FB_LVL2 + (size_t)l * 16, 1u) == 15u) {
                        u32* donep = ws + FB_DONE + (size_t)l * 1024;
                        #pragma unroll
                        for (int j = 0; j < 64; ++j)
                            agent_store(donep + j * 16, 1u);
                    }
                }
            }
        }
    } else {
        int ub = blockIdx.x - 128;           // NU = 1920, %8 == 0
        int x = ub & 7;
        for (int l = 0; l <= LAYERS; ++l) {
            if (l >= 1) fb_wait(ws, l, ub & 63, tid, 8);
            const u32* Sl = S + (size_t)l * WPL;
            f4* ob = (f4*)(out + (size_t)l * WGATES * BATCH);
            u32 ibeg = (u32)x * (F4L / 8) + (u32)(ub >> 3) * 256u + tid;
            u32 iend = (u32)x * (F4L / 8) + F4L / 8;
            for (u32 i = ibeg; i < iend; i += 240u * 256u)
                unpack_f4(Sl[i >> 3], (i & 7) * 4, ob + i);
        }
    }
}

// ---------------------------------------------------------------------------
// coop_v8: R13 proven kernel (ws too small for XCD mode). State at S_OFF_V8.
// ---------------------------------------------------------------------------
__global__ __launch_bounds__(256) void coop_v8(
        const int* __restrict__ src_idx,
        const int* __restrict__ cell_type,
        u32* __restrict__ ws,
        float* __restrict__ out,
        int NU)
{
    u32* S = ws + S_OFF_V8;
    int tid = threadIdx.x;
    __shared__ u32 stt[NTYPES];
    if (tid < NTYPES) stt[tid] = ws[tid];
    __syncthreads();

    if ((int)blockIdx.x < 128) {
        int g = blockIdx.x * 256 + tid;
        int sub = blockIdx.x & 15;
        for (int l = 1; l <= LAYERS; ++l) {
            const int4 s = ((const int4*)(src_idx + (size_t)(l - 1) * WGATES * 4))[g];
            u32 ttv = stt[cell_type[(size_t)(l - 1) * WGATES + g]];
            if (l > 1) fb_wait(ws, l - 1, sub, tid, 1);
            const uint4* Sp = (const uint4*)(S + (size_t)(l - 1) * WPL);
            uint4 A = Sp[(u32)s.x], B = Sp[(u32)s.y],
                  C = Sp[(u32)s.z], D = Sp[(u32)s.w];
            u32 m[16];
            lut_masks(ttv, m);
            u32 r0 = lut_mux(m, A.x, B.x, C.x, D.x);
            u32 r1 = lut_mux(m, A.y, B.y, C.y, D.y);
            u32 r2 = lut_mux(m, A.z, B.z, C.z, D.z);
            u32 r3 = lut_mux(m, A.w, B.w, C.w, D.w);
            u64* dst = (u64*)(S + (size_t)l * WPL + (size_t)g * 4);
            agent_store64(dst,     ((u64)r1 << 32) | r0);
            agent_store64(dst + 1, ((u64)r3 << 32) | r2);
            asm volatile("s_waitcnt vmcnt(0)" ::: "memory");
            __syncthreads();
            if (tid == 0) {
                u32* subp = ws + FB_SUB + (size_t)l * 1024 + sub * 16;
                if (agent_add(subp, 1u) == 7u) {
                    if (agent_add(ws + FB_LVL2 + (size_t)l * 16, 1u) == 15u) {
                        u32* donep = ws + FB_DONE + (size_t)l * 1024;
                        #pragma unroll
                        for (int j = 0; j < 64; ++j)
                            agent_store(donep + j * 16, 1u);
                    }
                }
            }
        }
    } else {
        int ub = blockIdx.x - 128;
        bool sliced = (NU & 7) == 0;
        int x = ub & 7;
        u32 per = (u32)(NU >> 3);
        for (int l = 0; l <= LAYERS; ++l) {
            if (l >= 1) fb_wait(ws, l, ub & 63, tid, 8);
            const u32* Sl = S + (size_t)l * WPL;
            f4* ob = (f4*)(out + (size_t)l * WGATES * BATCH);
            u32 ibeg, iend, istep;
            if (sliced) {
                ibeg = (u32)x * (F4L / 8) + (u32)(ub >> 3) * 256u + tid;
                iend = (u32)x * (F4L / 8) + F4L / 8;
                istep = per * 256u;
            } else {
                ibeg = (u32)ub * 256u + tid; iend = (u32)F4L; istep = (u32)NU * 256u;
            }
            for (u32 i = ibeg; i < iend; i += istep)
                unpack_f4(Sl[i >> 3], (i & 7) * 4, ob + i);
        }
    }
}

// ======================= R2 fallback path (proven) =========================
__global__ void pack_kernel_fb(const float* __restrict__ feature,
                               const float* __restrict__ activation,
                               float* __restrict__ out,
                               u32* __restrict__ tt_ws,
                               u32* __restrict__ buf0) {
    int t = blockIdx.x * 256 + threadIdx.x;
    if (blockIdx.x == 0 && threadIdx.x < NTYPES) {
        u32 tt = 0;
        #pragma unroll
        for (int m = 0; m < 16; ++m)
            tt |= (activation[threadIdx.x * 16 + m] != 0.0f ? 1u : 0u) << m;
        tt_ws[threadIdx.x] = tt;
    }
    float v = feature[t];
    out[t] = v;
    u64 m = __ballot(v != 0.0f);
    if ((t & 63) == 0)
        ((u64*)buf0)[t >> 6] = m;
}

__global__ void fused_kernel_fb(const u32* __restrict__ prev,
                                u32* __restrict__ next,
                                const int* __restrict__ src_idx,
                                const int* __restrict__ cell_type,
                                const u32* __restrict__ tt_ws,
                                const u32* __restrict__ upacked,
                                float* __restrict__ uout,
                                int do_compute)
{
    int tid = threadIdx.x;
    if (do_compute && blockIdx.x < 512) {
        int gl = tid >> 2, q = tid & 3;
        int wg = blockIdx.x * 64 + gl;
        const int4 s = ((const int4*)src_idx)[wg];
        u32 tt = tt_ws[cell_type[wg]];
        u32 m[16];
        lut_masks(tt, m);
        u32 a = prev[(size_t)s.x * 4 + q];
        u32 b = prev[(size_t)s.y * 4 + q];
        u32 c = prev[(size_t)s.z * 4 + q];
        u32 d = prev[(size_t)s.w * 4 + q];
        next[(size_t)wg * 4 + q] = lut_mux(m, a, b, c, d);
        return;
    }
    if (uout == nullptr) return;
    int ub = do_compute ? (int)blockIdx.x - 512 : (int)blockIdx.x;
    #pragma unroll
    for (int r = 0; r < 2; ++r) {
        int fi = ((ub * 2 + r) * 256 + tid) * 4;
        u32 wb = upacked[fi >> 5];
        int sh = fi & 31;
        f4 f;
        f.x = ((wb >> (sh    )) & 1) ? 1.0f : 0.0f;
        f.y = ((wb >> (sh + 1)) & 1) ? 1.0f : 0.0f;
        f.z = ((wb >> (sh + 2)) & 1) ? 1.0f : 0.0f;
        f.w = ((wb >> (sh + 3)) & 1) ? 1.0f : 0.0f;
        ((f4*)uout)[fi >> 2] = f;
    }
}

static void launch_fallback(const float* feature, const float* activation,
                            const int* src_idx, const int* cell_type,
                            float* out, void* d_ws, hipStream_t stream) {
    u32* tt_ws = (u32*)d_ws;
    u32* bufA = (u32*)((char*)d_ws + 1024);
    u32* bufB = (u32*)((char*)d_ws + 1024 + WGATES * 16);
    pack_kernel_fb<<<WGATES * BATCH / 256, 256, 0, stream>>>(
        feature, activation, out, tt_ws, bufA);
    for (int l = 1; l <= LAYERS; ++l) {
        u32* prev = ((l - 1) & 1) ? bufB : bufA;
        u32* next = ((l - 1) & 1) ? bufA : bufB;
        float* uout = (l >= 2) ? out + (size_t)(l - 1) * WGATES * BATCH : nullptr;
        fused_kernel_fb<<<512 + 2048, 256, 0, stream>>>(
            prev, next,
            src_idx + (size_t)(l - 1) * WGATES * 4,
            cell_type + (size_t)(l - 1) * WGATES,
            tt_ws, prev, uout, 1);
    }
    u32* s32 = ((LAYERS - 1) & 1) ? bufA : bufB;
    fused_kernel_fb<<<2048, 256, 0, stream>>>(
        s32, s32, src_idx, cell_type, tt_ws,
        s32, out + (size_t)LAYERS * WGATES * BATCH, 0);
}

extern "C" void kernel_launch(void* const* d_in, const int* in_sizes, int n_in,
                              void* d_out, int out_size, void* d_ws, size_t ws_size,
                              hipStream_t stream) {
    const float* feature    = (const float*)d_in[0];
    const float* activation = (const float*)d_in[1];
    const int*   src_idx    = (const int*)d_in[2];
    const int*   cell_type  = (const int*)d_in[3];
    float* out = (float*)d_out;
    u32* ws = (u32*)d_ws;

    int dev = 0, numCU = 0;
    (void)hipGetDevice(&dev);
    bool have_dev = hipDeviceGetAttribute(
        &numCU, hipDeviceAttributeMultiprocessorCount, dev) == hipSuccess;

    // --- try XCD-replicated path ---
    if (have_dev && ws_size >= WS_NEED_XCD) {
        int bpc = 0;
        if (hipOccupancyMaxActiveBlocksPerMultiprocessor(
                &bpc, (const void*)coop_xcd, 256, 0) == hipSuccess &&
            bpc * numCU >= 2048) {
            pack_main<<<WGATES * BATCH / 256, 256, 0, stream>>>(
                feature, activation, ws, 1);
            void* args[] = {(void*)&src_idx, (void*)&cell_type,
                            (void*)&ws, (void*)&out};
            if (hipLaunchCooperativeKernel((const void*)coop_xcd,
                    dim3(2048), dim3(256), args, 0, stream) == hipSuccess)
                return;
        }
    }
    // --- proven sc1 coop path ---
    if (have_dev && ws_size >= WS_NEED_V8) {
        int bpc = 0;
        if (hipOccupancyMaxActiveBlocksPerMultiprocessor(
                &bpc, (const void*)coop_v8, 256, 0) == hipSuccess) {
            int G = bpc * numCU;
            if (G > 2048) G = 2048;
            int NU = G - 128;
            if (NU >= 256) {
                pack_main<<<WGATES * BATCH / 256, 256, 0, stream>>>(
                    feature, activation, ws, 0);
                void* args[] = {(void*)&src_idx, (void*)&cell_type,
                                (void*)&ws, (void*)&out, (void*)&NU};
                if (hipLaunchCooperativeKernel((const void*)coop_v8,
                        dim3(G), dim3(256), args, 0, stream) == hipSuccess)
                    return;
            }
        }
    }
    launch_fallback(feature, activation, src_idx, cell_type, out, d_ws, stream);
}